// Round 16
// baseline (204.789 us; speedup 1.0000x reference)
//
#include <hip/hip_runtime.h>

#define NN 50000
#define NE 800000
#define C 128
#define H 16

typedef unsigned int u32;
typedef unsigned short u16;
typedef __fp16 h2 __attribute__((ext_vector_type(2)));
typedef __fp16 half8 __attribute__((ext_vector_type(8)));
typedef float f32x4 __attribute__((ext_vector_type(4)));

__device__ __forceinline__ h2 as_h2(u32 v) {
  union { u32 u; h2 h; } c; c.u = v; return c.h;
}
__device__ __forceinline__ u32 as_u32(h2 h) {
  union { u32 u; h2 h; } c; c.h = h; return c.u;
}
__device__ __forceinline__ half8 as_half8(uint4 v) {
  union { uint4 u; half8 h; } c; c.u = v; return c.h;
}
#define PK(a, b) __builtin_amdgcn_cvt_pkrtz((a), (b))
#define DOT2(w, f, acc) __builtin_amdgcn_fdot2((w), (f), (acc), false)

// ---------- silu + 7 cubic B-spline bases, closed form, NAMED outputs ----------
__device__ __forceinline__ void feat8s(float x, float& s, float& g0, float& g1,
                                       float& g2, float& g3, float& g4, float& g5,
                                       float& g6) {
  s = x / (1.f + __expf(-x));
  float t = (x + 2.5f) * 2.0f;
  float cf = floorf(t);
  int c = (int)cf;
  float u = t - cf;
  float u2 = u * u, u3 = u2 * u;
  const float k6 = 1.f / 6.f;
  float P0 = u3 * k6;
  float P1 = (1.f + 3.f * u + 3.f * u2 - 3.f * u3) * k6;
  float P2 = (4.f - 6.f * u2 + 3.f * u3) * k6;
  float om = 1.f - u;
  float P3 = om * om * om * k6;
  bool valid = (t >= 0.f) && (t < 10.f);
#define SPJ(G, J)                                   \
  {                                                 \
    float b = 0.f;                                  \
    b = (c == (J)) ? P0 : b;                        \
    b = (c == (J) + 1) ? P1 : b;                    \
    b = (c == (J) + 2) ? P2 : b;                    \
    b = (c == (J) + 3) ? P3 : b;                    \
    G = valid ? b : 0.f;                            \
  }
  SPJ(g0, 0) SPJ(g1, 1) SPJ(g2, 2) SPJ(g3, 3) SPJ(g4, 4) SPJ(g5, 5) SPJ(g6, 6)
#undef SPJ
}

__device__ __forceinline__ u16 f2bf(float v) {
  u32 b = __float_as_uint(v);
  return (u16)((b + 0x7fffu + ((b >> 16) & 1u)) >> 16);  // RNE
}
__device__ __forceinline__ u16 f2h(float v) {
  union { __fp16 h; u16 u; } c; c.h = (__fp16)v; return c.u;
}
__device__ __forceinline__ float blo(u32 v) { return __uint_as_float(v << 16); }
__device__ __forceinline__ float bhi(u32 v) { return __uint_as_float(v & 0xffff0000u); }

#define RLU(x, J) ((u32)__builtin_amdgcn_readlane((int)(x), (J)))
#define REP16(M) M(0) M(1) M(2) M(3) M(4) M(5) M(6) M(7) M(8) M(9) M(10) M(11) M(12) M(13) M(14) M(15)

// ---------- prep_w: f16 W + f16 KAN weights ----------
__global__ void prep_w(const float* __restrict__ W,
                       const float* __restrict__ bw0, const float* __restrict__ sw0,
                       const float* __restrict__ sc0,
                       const float* __restrict__ bw1, const float* __restrict__ sw1,
                       const float* __restrict__ sc1,
                       u32* __restrict__ W16, u16* __restrict__ p0h,
                       u16* __restrict__ p1h) {
  int i = blockIdx.x * blockDim.x + threadIdx.x;
  if (i < C * C / 2) {  // W row-major, packed f16 pairs along k
    int o = i >> 6, kp = i & 63;
    W16[i] = (u32)f2h(W[o * C + kp * 2]) | ((u32)f2h(W[o * C + kp * 2 + 1]) << 16);
  }
  if (i < H * C * 8) {
    int of = i >> 3, j = i & 7;
    float v = (j == 0) ? bw0[of] : sw0[of * 7 + (j - 1)] * sc0[of];
    p0h[i] = f2h(v);
  }
  if (i < C * H * 8) {
    int of = i >> 3, j = i & 7;
    float v = (j == 0) ? bw1[of] : sw1[of * 7 + (j - 1)] * sc1[of];
    p1h[i] = f2h(v);
  }
}

// ---------- count + slot capture ----------
__global__ void count_kernel(const int* __restrict__ dst, int* __restrict__ cnt,
                             int* __restrict__ slot) {
  int e = blockIdx.x * blockDim.x + threadIdx.x;
  if (e < NE) slot[e] = atomicAdd(&cnt[dst[e]], 1);
}

// ---------- scan1: block-local exclusive scan + block totals ----------
__global__ void scan1(const int* __restrict__ cnt, int* __restrict__ excl,
                      int* __restrict__ bsums, int n) {
  int i = blockIdx.x * 256 + threadIdx.x;
  int v = (i < n) ? cnt[i] : 0;
  int lane = threadIdx.x & 63, wid = threadIdx.x >> 6;
  int s = v;
#pragma unroll
  for (int o = 1; o < 64; o <<= 1) {
    int t = __shfl_up(s, o, 64);
    if (lane >= o) s += t;
  }
  __shared__ int wsum[4];
  if (lane == 63) wsum[wid] = s;
  __syncthreads();
  int woff = 0;
  for (int w = 0; w < wid; ++w) woff += wsum[w];
  if (i < n) excl[i] = woff + s - v;
  if (threadIdx.x == 255) bsums[blockIdx.x] = woff + s;
}

// ---------- scan3 (scan2 folded in) ----------
__global__ void scan3(const int* __restrict__ excl, const int* __restrict__ bsums,
                      const int* __restrict__ cnt, int* __restrict__ row_start,
                      float* __restrict__ dinv, int n, int nb) {
  __shared__ int red[256];
  const int t = threadIdx.x;
  red[t] = (t < nb && t < (int)blockIdx.x) ? bsums[t] : 0;
  __syncthreads();
#pragma unroll
  for (int s = 128; s > 0; s >>= 1) {
    if (t < s) red[t] += red[t + s];
    __syncthreads();
  }
  const int boff = red[0];
  const int i = blockIdx.x * 256 + t;
  if (i < n) {
    row_start[i] = excl[i] + boff;
    dinv[i] = rsqrtf((float)(cnt[i] + 1));
  }
  if (blockIdx.x == 0 && t == 0) row_start[n] = NE;
}

// ---------- xs_prep: xs[n][c] = bf16(x[n][c] * dinv[n]) packed ----------
__global__ void xs_prep(const float* __restrict__ x, const float* __restrict__ dinv,
                        u32* __restrict__ xs) {
  int i = blockIdx.x * blockDim.x + threadIdx.x;  // one float4 per thread
  if (i < NN * C / 4) {
    int n = i >> 5;  // 32 float4 per row
    float dv = dinv[n];
    float4 v = *(const float4*)&x[(size_t)i * 4];
    u32 lo = (u32)f2bf(v.x * dv) | ((u32)f2bf(v.y * dv) << 16);
    u32 hi = (u32)f2bf(v.z * dv) | ((u32)f2bf(v.w * dv) << 16);
    *(uint2*)&xs[(size_t)i * 2] = make_uint2(lo, hi);
  }
}

// ---------- CSR fill: atomic-free 4B scatter per edge ----------
__global__ void fill_kernel(const int* __restrict__ src, const int* __restrict__ dst,
                            const int* __restrict__ slot,
                            const int* __restrict__ row_start, int* __restrict__ csr) {
  int e = blockIdx.x * blockDim.x + threadIdx.x;
  if (e < NE) csr[row_start[dst[e]] + slot[e]] = src[e];
}

// ---------- aggregation: pure gather+add (weights pre-folded), f16 out ----------
__global__ __launch_bounds__(256, 8) void agg_kernel(
    const u32* __restrict__ xs, const int* __restrict__ csr,
    const int* __restrict__ row_start, const float* __restrict__ dinv,
    u32* __restrict__ ax16) {
  const int l = threadIdx.x & 63;
  const int node = blockIdx.x * 4 + (threadIdx.x >> 6);
  const int e0 = row_start[node], e1 = row_start[node + 1];
  const float dn = dinv[node];
  const u32 vs = xs[(size_t)node * 64 + l];
  float a0 = blo(vs), a1 = bhi(vs);
  int e = e0;
  for (; e + 8 <= e1; e += 8) {
    const int s0 = csr[e], s1 = csr[e + 1], s2 = csr[e + 2], s3 = csr[e + 3];
    const int s4 = csr[e + 4], s5 = csr[e + 5], s6 = csr[e + 6], s7 = csr[e + 7];
    const u32 v0 = xs[(size_t)s0 * 64 + l];
    const u32 v1 = xs[(size_t)s1 * 64 + l];
    const u32 v2 = xs[(size_t)s2 * 64 + l];
    const u32 v3 = xs[(size_t)s3 * 64 + l];
    const u32 v4 = xs[(size_t)s4 * 64 + l];
    const u32 v5 = xs[(size_t)s5 * 64 + l];
    const u32 v6 = xs[(size_t)s6 * 64 + l];
    const u32 v7 = xs[(size_t)s7 * 64 + l];
    a0 += blo(v0); a1 += bhi(v0);
    a0 += blo(v1); a1 += bhi(v1);
    a0 += blo(v2); a1 += bhi(v2);
    a0 += blo(v3); a1 += bhi(v3);
    a0 += blo(v4); a1 += bhi(v4);
    a0 += blo(v5); a1 += bhi(v5);
    a0 += blo(v6); a1 += bhi(v6);
    a0 += blo(v7); a1 += bhi(v7);
  }
  for (; e < e1; ++e) {
    const u32 v = xs[(size_t)csr[e] * 64 + l];
    a0 += blo(v);
    a1 += bhi(v);
  }
  a0 *= dn;
  a1 *= dn;
  ax16[(size_t)node * 64 + l] = (u32)f2h(a0) | ((u32)f2h(a1) << 16);
}

// ---------- GEMM via MFMA f16: h16 = ax16 @ W16^T (r14-verified layout) ----------
__global__ __launch_bounds__(256) void gemm_mfma(const u32* __restrict__ ax16,
                                                 const u32* __restrict__ W16,
                                                 __fp16* __restrict__ h16) {
  const int wv = threadIdx.x >> 6;
  const int l = threadIdx.x & 63;
  const int m0 = (blockIdx.x * 4 + wv) * 16;
  if (m0 >= NN) return;
  const int rc = l & 15, kb = l >> 4;
  uint4 a[4];
#pragma unroll
  for (int s = 0; s < 4; ++s)
    a[s] = *(const uint4*)&ax16[(size_t)(m0 + rc) * 64 + s * 16 + kb * 4];
  f32x4 acc[8];
#pragma unroll
  for (int t = 0; t < 8; ++t) acc[t] = (f32x4){0.f, 0.f, 0.f, 0.f};
#pragma unroll
  for (int t = 0; t < 8; ++t) {
#pragma unroll
    for (int s = 0; s < 4; ++s) {
      uint4 b = *(const uint4*)&W16[(size_t)(t * 16 + rc) * 64 + s * 16 + kb * 4];
      acc[t] = __builtin_amdgcn_mfma_f32_16x16x32_f16(as_half8(a[s]), as_half8(b),
                                                      acc[t], 0, 0, 0);
    }
  }
#pragma unroll
  for (int t = 0; t < 8; ++t) {
#pragma unroll
    for (int r = 0; r < 4; ++r) {
      h16[(size_t)(m0 + kb * 4 + r) * C + t * 16 + rc] = (__fp16)acc[t][r];
    }
  }
}

// ---------- kanF: merged KAN0+KAN1, 1024-thread blocks ----------
// r15: 512-thr blocks + 64KB LDS -> 2 blocks/CU = 16 waves/CU (27.8% occ),
// VALUBusy 70%. 1024-thr blocks keep 64KB/block but reach 32 waves/CU
// (2 blocks x 16 waves); VGPR 52 <= 64 so 8 waves/SIMD is legal.
__global__ __launch_bounds__(1024) void kanF(
    const __fp16* __restrict__ h16, const float* __restrict__ bias,
    const u16* __restrict__ p0h, const u16* __restrict__ p1h,
    float* __restrict__ out) {
  __shared__ u32 P0s[8192];   // 32 KB: uint4 record J*128 + f
  __shared__ u32 P1s[8192];   // 32 KB: uint4 record J*128 + o (transposed)
  const int tid = threadIdx.x;
  {
    const uint4* g0 = (const uint4*)p0h;
    const uint4* g1 = (const uint4*)p1h;
    uint4* s0 = (uint4*)P0s;
    uint4* s1 = (uint4*)P1s;
    for (int r = tid; r < 2048; r += 1024) {
      s0[r] = g0[r];
      int oo = r >> 4, j = r & 15;
      s1[j * 128 + oo] = g1[r];
    }
  }
  __syncthreads();
  const int o = tid & 63;
  const int wave = tid >> 6;                 // 0..15
  const float bLo = bias[o], bHi = bias[o + 64];
  const bool b1 = (o & 1), b2 = (o & 2), b4 = (o & 4), b8 = (o & 8);
  const int stride = gridDim.x * 16;
  for (int pr = blockIdx.x * 16 + wave; pr < NN / 2; pr += stride) {
    const int nodeA = pr * 2, nodeB = nodeA + 1;
    float t0, t1, t2, t3, t4, t5, t6, t7;
    feat8s((float)h16[(size_t)nodeA * C + o] + bLo, t0, t1, t2, t3, t4, t5, t6, t7);
    h2 aA0 = PK(t0, t1), aA1 = PK(t2, t3), aA2 = PK(t4, t5), aA3 = PK(t6, t7);
    feat8s((float)h16[(size_t)nodeA * C + o + 64] + bHi, t0, t1, t2, t3, t4, t5, t6, t7);
    h2 bA0 = PK(t0, t1), bA1 = PK(t2, t3), bA2 = PK(t4, t5), bA3 = PK(t6, t7);
    feat8s((float)h16[(size_t)nodeB * C + o] + bLo, t0, t1, t2, t3, t4, t5, t6, t7);
    h2 aB0 = PK(t0, t1), aB1 = PK(t2, t3), aB2 = PK(t4, t5), aB3 = PK(t6, t7);
    feat8s((float)h16[(size_t)nodeB * C + o + 64] + bHi, t0, t1, t2, t3, t4, t5, t6, t7);
    h2 bB0 = PK(t0, t1), bB1 = PK(t2, t3), bB2 = PK(t4, t5), bB3 = PK(t6, t7);
#define K0J(J)                                                                 \
    float pA##J, pB##J;                                                        \
    {                                                                          \
      uint4 ra = *(const uint4*)&P0s[(J) * 512 + o * 4];                       \
      uint4 rb = *(const uint4*)&P0s[(J) * 512 + (o + 64) * 4];                \
      float vA = DOT2(as_h2(ra.x), aA0, 0.f);                                  \
      vA = DOT2(as_h2(ra.y), aA1, vA);                                         \
      vA = DOT2(as_h2(ra.z), aA2, vA);                                         \
      vA = DOT2(as_h2(ra.w), aA3, vA);                                         \
      vA = DOT2(as_h2(rb.x), bA0, vA);                                         \
      vA = DOT2(as_h2(rb.y), bA1, vA);                                         \
      vA = DOT2(as_h2(rb.z), bA2, vA);                                         \
      pA##J = DOT2(as_h2(rb.w), bA3, vA);                                      \
      float vB = DOT2(as_h2(ra.x), aB0, 0.f);                                  \
      vB = DOT2(as_h2(ra.y), aB1, vB);                                         \
      vB = DOT2(as_h2(ra.z), aB2, vB);                                         \
      vB = DOT2(as_h2(ra.w), aB3, vB);                                         \
      vB = DOT2(as_h2(rb.x), bB0, vB);                                         \
      vB = DOT2(as_h2(rb.y), bB1, vB);                                         \
      vB = DOT2(as_h2(rb.z), bB2, vB);                                         \
      pB##J = DOT2(as_h2(rb.w), bB3, vB);                                      \
      __builtin_amdgcn_sched_barrier(0);                                      \
    }
    REP16(K0J)
#undef K0J
#define BFLY(p0_, p1_, p2_, p3_, p4_, p5_, p6_, p7_, p8_, p9_, p10_, p11_,     \
             p12_, p13_, p14_, p15_, OUTV)                                     \
    {                                                                          \
      float q0 = (b1 ? p1_ : p0_) + __shfl_xor(b1 ? p0_ : p1_, 1, 64);         \
      float q1 = (b1 ? p3_ : p2_) + __shfl_xor(b1 ? p2_ : p3_, 1, 64);         \
      float q2 = (b1 ? p5_ : p4_) + __shfl_xor(b1 ? p4_ : p5_, 1, 64);         \
      float q3 = (b1 ? p7_ : p6_) + __shfl_xor(b1 ? p6_ : p7_, 1, 64);         \
      float q4 = (b1 ? p9_ : p8_) + __shfl_xor(b1 ? p8_ : p9_, 1, 64);         \
      float q5 = (b1 ? p11_ : p10_) + __shfl_xor(b1 ? p10_ : p11_, 1, 64);     \
      float q6 = (b1 ? p13_ : p12_) + __shfl_xor(b1 ? p12_ : p13_, 1, 64);     \
      float q7 = (b1 ? p15_ : p14_) + __shfl_xor(b1 ? p14_ : p15_, 1, 64);     \
      float r0 = (b2 ? q1 : q0) + __shfl_xor(b2 ? q0 : q1, 2, 64);             \
      float r1 = (b2 ? q3 : q2) + __shfl_xor(b2 ? q2 : q3, 2, 64);             \
      float r2 = (b2 ? q5 : q4) + __shfl_xor(b2 ? q4 : q5, 2, 64);             \
      float r3 = (b2 ? q7 : q6) + __shfl_xor(b2 ? q6 : q7, 2, 64);             \
      float s0 = (b4 ? r1 : r0) + __shfl_xor(b4 ? r0 : r1, 4, 64);             \
      float s1 = (b4 ? r3 : r2) + __shfl_xor(b4 ? r2 : r3, 4, 64);             \
      float t_ = (b8 ? s1 : s0) + __shfl_xor(b8 ? s0 : s1, 8, 64);             \
      t_ += __shfl_xor(t_, 16, 64);                                            \
      t_ += __shfl_xor(t_, 32, 64);                                            \
      OUTV = t_;                                                               \
    }
    float hA, hB;
    BFLY(pA0, pA1, pA2, pA3, pA4, pA5, pA6, pA7, pA8, pA9, pA10, pA11, pA12,
         pA13, pA14, pA15, hA)
    BFLY(pB0, pB1, pB2, pB3, pB4, pB5, pB6, pB7, pB8, pB9, pB10, pB11, pB12,
         pB13, pB14, pB15, hB)
#undef BFLY
    // lane o holds hidden value j16 = o&15 for both nodes -> straight into KAN1
    feat8s(hA, t0, t1, t2, t3, t4, t5, t6, t7);
    u32 uA0 = as_u32(PK(t0, t1)), uA1 = as_u32(PK(t2, t3));
    u32 uA2 = as_u32(PK(t4, t5)), uA3 = as_u32(PK(t6, t7));
    feat8s(hB, t0, t1, t2, t3, t4, t5, t6, t7);
    u32 uB0 = as_u32(PK(t0, t1)), uB1 = as_u32(PK(t2, t3));
    u32 uB2 = as_u32(PK(t4, t5)), uB3 = as_u32(PK(t6, t7));
    float accLoA = 0.f, accHiA = 0.f, accLoB = 0.f, accHiB = 0.f;
#define K1J(J)                                                                 \
    {                                                                          \
      uint4 ra = *(const uint4*)&P1s[(J) * 512 + o * 4];                       \
      uint4 rb = *(const uint4*)&P1s[(J) * 512 + (o + 64) * 4];                \
      h2 qA0 = as_h2(RLU(uA0, J)), qA1 = as_h2(RLU(uA1, J));                   \
      h2 qA2 = as_h2(RLU(uA2, J)), qA3 = as_h2(RLU(uA3, J));                   \
      h2 qB0 = as_h2(RLU(uB0, J)), qB1 = as_h2(RLU(uB1, J));                   \
      h2 qB2 = as_h2(RLU(uB2, J)), qB3 = as_h2(RLU(uB3, J));                   \
      accLoA = DOT2(as_h2(ra.x), qA0, accLoA);                                 \
      accLoA = DOT2(as_h2(ra.y), qA1, accLoA);                                 \
      accLoA = DOT2(as_h2(ra.z), qA2, accLoA);                                 \
      accLoA = DOT2(as_h2(ra.w), qA3, accLoA);                                 \
      accHiA = DOT2(as_h2(rb.x), qA0, accHiA);                                 \
      accHiA = DOT2(as_h2(rb.y), qA1, accHiA);                                 \
      accHiA = DOT2(as_h2(rb.z), qA2, accHiA);                                 \
      accHiA = DOT2(as_h2(rb.w), qA3, accHiA);                                 \
      accLoB = DOT2(as_h2(ra.x), qB0, accLoB);                                 \
      accLoB = DOT2(as_h2(ra.y), qB1, accLoB);                                 \
      accLoB = DOT2(as_h2(ra.z), qB2, accLoB);                                 \
      accLoB = DOT2(as_h2(ra.w), qB3, accLoB);                                 \
      accHiB = DOT2(as_h2(rb.x), qB0, accHiB);                                 \
      accHiB = DOT2(as_h2(rb.y), qB1, accHiB);                                 \
      accHiB = DOT2(as_h2(rb.z), qB2, accHiB);                                 \
      accHiB = DOT2(as_h2(rb.w), qB3, accHiB);                                 \
      __builtin_amdgcn_sched_barrier(0);                                      \
    }
    REP16(K1J)
#undef K1J
    out[(size_t)nodeA * C + o] = accLoA;
    out[(size_t)nodeA * C + o + 64] = accHiA;
    out[(size_t)nodeB * C + o] = accLoB;
    out[(size_t)nodeB * C + o + 64] = accHiB;
  }
}

extern "C" void kernel_launch(void* const* d_in, const int* in_sizes, int n_in,
                              void* d_out, int out_size, void* d_ws, size_t ws_size,
                              hipStream_t stream) {
  const float* x   = (const float*)d_in[0];
  const int*   ei  = (const int*)d_in[1];
  const float* gw  = (const float*)d_in[2];
  const float* gb  = (const float*)d_in[3];
  const float* bw0 = (const float*)d_in[4];
  const float* sw0 = (const float*)d_in[5];
  const float* sc0 = (const float*)d_in[6];
  const float* bw1 = (const float*)d_in[7];
  const float* sw1 = (const float*)d_in[8];
  const float* sc1 = (const float*)d_in[9];
  float* out = (float*)d_out;

  char* p = (char*)d_ws;
  u32* W16 = (u32*)p;         p += C * C * 2;            // 32 KB
  u16* p0h = (u16*)p;         p += H * C * 8 * 2;        // 32 KB
  u16* p1h = (u16*)p;         p += C * H * 8 * 2;        // 32 KB
  float* dinv = (float*)p;    p += NN * 4;
  int* cnt = (int*)p;         p += NN * 4;
  int* excl = (int*)p;        p += NN * 4;
  int* bsums = (int*)p;       p += 256 * 4;
  int* row_start = (int*)p;   p += (NN + 4) * 4;
  int* slot = (int*)p;        p += (size_t)NE * 4;       // 3.2 MB
  int* csr = (int*)p;         p += (size_t)NE * 4;       // 3.2 MB
  u32* xs = (u32*)p;          p += (size_t)NN * C * 2;   // 12.8 MB
  u32* ax16 = (u32*)p;        p += (size_t)NN * C * 2;   // 12.8 MB
  __fp16* h16 = (__fp16*)p;   p += (size_t)NN * C * 2;   // 12.8 MB

  const int* src = ei;
  const int* dst = ei + NE;

  hipMemsetAsync(cnt, 0, NN * 4, stream);

  prep_w<<<64, 256, 0, stream>>>(gw, bw0, sw0, sc0, bw1, sw1, sc1, W16, p0h, p1h);
  count_kernel<<<(NE + 255) / 256, 256, 0, stream>>>(dst, cnt, slot);
  scan1<<<196, 256, 0, stream>>>(cnt, excl, bsums, NN);
  scan3<<<196, 256, 0, stream>>>(excl, bsums, cnt, row_start, dinv, NN, 196);
  xs_prep<<<(NN * C / 4 + 255) / 256, 256, 0, stream>>>(x, dinv, xs);
  fill_kernel<<<(NE + 255) / 256, 256, 0, stream>>>(src, dst, slot, row_start, csr);
  agg_kernel<<<NN / 4, 256, 0, stream>>>(xs, csr, row_start, dinv, ax16);
  gemm_mfma<<<(NN + 63) / 64, 256, 0, stream>>>(ax16, W16, h16);
  kanF<<<512, 1024, 0, stream>>>(h16, gb, p0h, p1h, out);
}

// Round 17
// 183.778 us; speedup vs baseline: 1.1143x; 1.1143x over previous
//
#include <hip/hip_runtime.h>

#define NN 50000
#define NE 800000
#define C 128
#define H 16

typedef unsigned int u32;
typedef unsigned short u16;
typedef __fp16 h2 __attribute__((ext_vector_type(2)));
typedef __fp16 half8 __attribute__((ext_vector_type(8)));
typedef float f32x4 __attribute__((ext_vector_type(4)));

__device__ __forceinline__ h2 as_h2(u32 v) {
  union { u32 u; h2 h; } c; c.u = v; return c.h;
}
__device__ __forceinline__ u32 as_u32(h2 h) {
  union { u32 u; h2 h; } c; c.h = h; return c.u;
}
__device__ __forceinline__ half8 as_half8(uint4 v) {
  union { uint4 u; half8 h; } c; c.u = v; return c.h;
}
#define PK(a, b) __builtin_amdgcn_cvt_pkrtz((a), (b))

// ---------- silu + 7 cubic B-spline bases, closed form, NAMED outputs ----------
__device__ __forceinline__ void feat8s(float x, float& s, float& g0, float& g1,
                                       float& g2, float& g3, float& g4, float& g5,
                                       float& g6) {
  s = x / (1.f + __expf(-x));
  float t = (x + 2.5f) * 2.0f;
  float cf = floorf(t);
  int c = (int)cf;
  float u = t - cf;
  float u2 = u * u, u3 = u2 * u;
  const float k6 = 1.f / 6.f;
  float P0 = u3 * k6;
  float P1 = (1.f + 3.f * u + 3.f * u2 - 3.f * u3) * k6;
  float P2 = (4.f - 6.f * u2 + 3.f * u3) * k6;
  float om = 1.f - u;
  float P3 = om * om * om * k6;
  bool valid = (t >= 0.f) && (t < 10.f);
#define SPJ(G, J)                                   \
  {                                                 \
    float b = 0.f;                                  \
    b = (c == (J)) ? P0 : b;                        \
    b = (c == (J) + 1) ? P1 : b;                    \
    b = (c == (J) + 2) ? P2 : b;                    \
    b = (c == (J) + 3) ? P3 : b;                    \
    G = valid ? b : 0.f;                            \
  }
  SPJ(g0, 0) SPJ(g1, 1) SPJ(g2, 2) SPJ(g3, 3) SPJ(g4, 4) SPJ(g5, 5) SPJ(g6, 6)
#undef SPJ
}

__device__ __forceinline__ u16 f2bf(float v) {
  u32 b = __float_as_uint(v);
  return (u16)((b + 0x7fffu + ((b >> 16) & 1u)) >> 16);  // RNE
}
__device__ __forceinline__ u16 f2h(float v) {
  union { __fp16 h; u16 u; } c; c.h = (__fp16)v; return c.u;
}
__device__ __forceinline__ float blo(u32 v) { return __uint_as_float(v << 16); }
__device__ __forceinline__ float bhi(u32 v) { return __uint_as_float(v & 0xffff0000u); }

// build a half8 A-fragment from one feat8s evaluation
__device__ __forceinline__ uint4 featfrag(float x) {
  float t0, t1, t2, t3, t4, t5, t6, t7;
  feat8s(x, t0, t1, t2, t3, t4, t5, t6, t7);
  uint4 r;
  r.x = as_u32(PK(t0, t1));
  r.y = as_u32(PK(t2, t3));
  r.z = as_u32(PK(t4, t5));
  r.w = as_u32(PK(t6, t7));
  return r;
}

// ---------- prep_w: f16 W + f16 KAN weights ----------
__global__ void prep_w(const float* __restrict__ W,
                       const float* __restrict__ bw0, const float* __restrict__ sw0,
                       const float* __restrict__ sc0,
                       const float* __restrict__ bw1, const float* __restrict__ sw1,
                       const float* __restrict__ sc1,
                       u32* __restrict__ W16, u16* __restrict__ p0h,
                       u16* __restrict__ p1h) {
  int i = blockIdx.x * blockDim.x + threadIdx.x;
  if (i < C * C / 2) {  // W row-major, packed f16 pairs along k
    int o = i >> 6, kp = i & 63;
    W16[i] = (u32)f2h(W[o * C + kp * 2]) | ((u32)f2h(W[o * C + kp * 2 + 1]) << 16);
  }
  if (i < H * C * 8) {  // p0h[hidden][k=f*8+j]
    int of = i >> 3, j = i & 7;
    float v = (j == 0) ? bw0[of] : sw0[of * 7 + (j - 1)] * sc0[of];
    p0h[i] = f2h(v);
  }
  if (i < C * H * 8) {  // p1h[out][k=j*8+t]
    int of = i >> 3, j = i & 7;
    float v = (j == 0) ? bw1[of] : sw1[of * 7 + (j - 1)] * sc1[of];
    p1h[i] = f2h(v);
  }
}

// ---------- count + slot capture ----------
__global__ void count_kernel(const int* __restrict__ dst, int* __restrict__ cnt,
                             int* __restrict__ slot) {
  int e = blockIdx.x * blockDim.x + threadIdx.x;
  if (e < NE) slot[e] = atomicAdd(&cnt[dst[e]], 1);
}

// ---------- scan1 ----------
__global__ void scan1(const int* __restrict__ cnt, int* __restrict__ excl,
                      int* __restrict__ bsums, int n) {
  int i = blockIdx.x * 256 + threadIdx.x;
  int v = (i < n) ? cnt[i] : 0;
  int lane = threadIdx.x & 63, wid = threadIdx.x >> 6;
  int s = v;
#pragma unroll
  for (int o = 1; o < 64; o <<= 1) {
    int t = __shfl_up(s, o, 64);
    if (lane >= o) s += t;
  }
  __shared__ int wsum[4];
  if (lane == 63) wsum[wid] = s;
  __syncthreads();
  int woff = 0;
  for (int w = 0; w < wid; ++w) woff += wsum[w];
  if (i < n) excl[i] = woff + s - v;
  if (threadIdx.x == 255) bsums[blockIdx.x] = woff + s;
}

// ---------- scan3 ----------
__global__ void scan3(const int* __restrict__ excl, const int* __restrict__ bsums,
                      const int* __restrict__ cnt, int* __restrict__ row_start,
                      float* __restrict__ dinv, int n, int nb) {
  __shared__ int red[256];
  const int t = threadIdx.x;
  red[t] = (t < nb && t < (int)blockIdx.x) ? bsums[t] : 0;
  __syncthreads();
#pragma unroll
  for (int s = 128; s > 0; s >>= 1) {
    if (t < s) red[t] += red[t + s];
    __syncthreads();
  }
  const int boff = red[0];
  const int i = blockIdx.x * 256 + t;
  if (i < n) {
    row_start[i] = excl[i] + boff;
    dinv[i] = rsqrtf((float)(cnt[i] + 1));
  }
  if (blockIdx.x == 0 && t == 0) row_start[n] = NE;
}

// ---------- xs_prep ----------
__global__ void xs_prep(const float* __restrict__ x, const float* __restrict__ dinv,
                        u32* __restrict__ xs) {
  int i = blockIdx.x * blockDim.x + threadIdx.x;
  if (i < NN * C / 4) {
    int n = i >> 5;
    float dv = dinv[n];
    float4 v = *(const float4*)&x[(size_t)i * 4];
    u32 lo = (u32)f2bf(v.x * dv) | ((u32)f2bf(v.y * dv) << 16);
    u32 hi = (u32)f2bf(v.z * dv) | ((u32)f2bf(v.w * dv) << 16);
    *(uint2*)&xs[(size_t)i * 2] = make_uint2(lo, hi);
  }
}

// ---------- CSR fill: atomic-free 4B scatter ----------
__global__ void fill_kernel(const int* __restrict__ src, const int* __restrict__ dst,
                            const int* __restrict__ slot,
                            const int* __restrict__ row_start, int* __restrict__ csr) {
  int e = blockIdx.x * blockDim.x + threadIdx.x;
  if (e < NE) csr[row_start[dst[e]] + slot[e]] = src[e];
}

// ---------- aggregation ----------
__global__ __launch_bounds__(256, 8) void agg_kernel(
    const u32* __restrict__ xs, const int* __restrict__ csr,
    const int* __restrict__ row_start, const float* __restrict__ dinv,
    u32* __restrict__ ax16) {
  const int l = threadIdx.x & 63;
  const int node = blockIdx.x * 4 + (threadIdx.x >> 6);
  const int e0 = row_start[node], e1 = row_start[node + 1];
  const float dn = dinv[node];
  const u32 vs = xs[(size_t)node * 64 + l];
  float a0 = blo(vs), a1 = bhi(vs);
  int e = e0;
  for (; e + 8 <= e1; e += 8) {
    const int s0 = csr[e], s1 = csr[e + 1], s2 = csr[e + 2], s3 = csr[e + 3];
    const int s4 = csr[e + 4], s5 = csr[e + 5], s6 = csr[e + 6], s7 = csr[e + 7];
    const u32 v0 = xs[(size_t)s0 * 64 + l];
    const u32 v1 = xs[(size_t)s1 * 64 + l];
    const u32 v2 = xs[(size_t)s2 * 64 + l];
    const u32 v3 = xs[(size_t)s3 * 64 + l];
    const u32 v4 = xs[(size_t)s4 * 64 + l];
    const u32 v5 = xs[(size_t)s5 * 64 + l];
    const u32 v6 = xs[(size_t)s6 * 64 + l];
    const u32 v7 = xs[(size_t)s7 * 64 + l];
    a0 += blo(v0); a1 += bhi(v0);
    a0 += blo(v1); a1 += bhi(v1);
    a0 += blo(v2); a1 += bhi(v2);
    a0 += blo(v3); a1 += bhi(v3);
    a0 += blo(v4); a1 += bhi(v4);
    a0 += blo(v5); a1 += bhi(v5);
    a0 += blo(v6); a1 += bhi(v6);
    a0 += blo(v7); a1 += bhi(v7);
  }
  for (; e < e1; ++e) {
    const u32 v = xs[(size_t)csr[e] * 64 + l];
    a0 += blo(v);
    a1 += bhi(v);
  }
  a0 *= dn;
  a1 *= dn;
  ax16[(size_t)node * 64 + l] = (u32)f2h(a0) | ((u32)f2h(a1) << 16);
}

// ---------- GEMM via MFMA f16: h16 = ax16 @ W16^T + bias ----------
__global__ __launch_bounds__(256) void gemm_mfma(const u32* __restrict__ ax16,
                                                 const u32* __restrict__ W16,
                                                 const float* __restrict__ bias,
                                                 __fp16* __restrict__ h16) {
  const int wv = threadIdx.x >> 6;
  const int l = threadIdx.x & 63;
  const int m0 = (blockIdx.x * 4 + wv) * 16;
  if (m0 >= NN) return;
  const int rc = l & 15, kb = l >> 4;
  uint4 a[4];
#pragma unroll
  for (int s = 0; s < 4; ++s)
    a[s] = *(const uint4*)&ax16[(size_t)(m0 + rc) * 64 + s * 16 + kb * 4];
  f32x4 acc[8];
#pragma unroll
  for (int t = 0; t < 8; ++t) acc[t] = (f32x4){0.f, 0.f, 0.f, 0.f};
#pragma unroll
  for (int t = 0; t < 8; ++t) {
#pragma unroll
    for (int s = 0; s < 4; ++s) {
      uint4 b = *(const uint4*)&W16[(size_t)(t * 16 + rc) * 64 + s * 16 + kb * 4];
      acc[t] = __builtin_amdgcn_mfma_f32_16x16x32_f16(as_half8(a[s]), as_half8(b),
                                                      acc[t], 0, 0, 0);
    }
  }
#pragma unroll
  for (int t = 0; t < 8; ++t) {
    const float bo = bias[t * 16 + rc];
#pragma unroll
    for (int r = 0; r < 4; ++r) {
      h16[(size_t)(m0 + kb * 4 + r) * C + t * 16 + rc] = (__fp16)(acc[t][r] + bo);
    }
  }
}

// ---------- kan_mfma: both KAN layers on the matrix pipe ----------
// K0: hid[16n][16h] = feat0[16n][K=1024] @ p0h[16h][1024]^T, 32 MFMA steps.
//   A-frag(s): lane(rc,kb) = feat8s(h16[m0+rc][f=s*4+kb]) -> 8 contiguous k. 
//   (k = f*8 + basis_j matches p0h linear layout hidden*1024 + f*8 + j.)
// transpose hid via per-wave LDS tile (D layout: node=(l>>4)*4+r, hidden=l&15).
// K1: out[16n][128] = feat1[16n][K=128] @ p1h[128o][128]^T, 8x4 MFMA.
__global__ __launch_bounds__(256) void kan_mfma(
    const __fp16* __restrict__ h16, const u16* __restrict__ p0h,
    const u16* __restrict__ p1h, float* __restrict__ out) {
  __shared__ float hidT[4][16][17];
  const int wv = threadIdx.x >> 6;
  const int l = threadIdx.x & 63;
  const int m0 = (blockIdx.x * 4 + wv) * 16;
  if (m0 >= NN) return;
  const int rc = l & 15, kb = l >> 4;
  // ---- K0 ----
  const __fp16* hrow = &h16[(size_t)(m0 + rc) * C];
  f32x4 acc0 = (f32x4){0.f, 0.f, 0.f, 0.f};
#pragma unroll
  for (int s = 0; s < 32; ++s) {
    uint4 au = featfrag((float)hrow[s * 4 + kb]);
    uint4 bu = *(const uint4*)&p0h[rc * 1024 + s * 32 + kb * 8];
    acc0 = __builtin_amdgcn_mfma_f32_16x16x32_f16(as_half8(au), as_half8(bu),
                                                  acc0, 0, 0, 0);
  }
  // ---- transpose hid within the wave via LDS ----
#pragma unroll
  for (int r = 0; r < 4; ++r) hidT[wv][kb * 4 + r][rc] = acc0[r];
  __builtin_amdgcn_s_waitcnt(0);  // lgkmcnt(0): wave-local LDS ordering
  // ---- K1 A-fragments: feat8s of hid[node rc][hidden s*4+kb] ----
  uint4 af0 = featfrag(hidT[wv][rc][0 * 4 + kb]);
  uint4 af1 = featfrag(hidT[wv][rc][1 * 4 + kb]);
  uint4 af2 = featfrag(hidT[wv][rc][2 * 4 + kb]);
  uint4 af3 = featfrag(hidT[wv][rc][3 * 4 + kb]);
  // ---- K1: 8 output tiles x 4 k-steps ----
  f32x4 acc1[8];
#pragma unroll
  for (int t = 0; t < 8; ++t) acc1[t] = (f32x4){0.f, 0.f, 0.f, 0.f};
#pragma unroll
  for (int t = 0; t < 8; ++t) {
    const u16* prow = &p1h[(size_t)(t * 16 + rc) * 128];
    uint4 b0 = *(const uint4*)&prow[0 * 32 + kb * 8];
    uint4 b1 = *(const uint4*)&prow[1 * 32 + kb * 8];
    uint4 b2 = *(const uint4*)&prow[2 * 32 + kb * 8];
    uint4 b3 = *(const uint4*)&prow[3 * 32 + kb * 8];
    acc1[t] = __builtin_amdgcn_mfma_f32_16x16x32_f16(as_half8(af0), as_half8(b0), acc1[t], 0, 0, 0);
    acc1[t] = __builtin_amdgcn_mfma_f32_16x16x32_f16(as_half8(af1), as_half8(b1), acc1[t], 0, 0, 0);
    acc1[t] = __builtin_amdgcn_mfma_f32_16x16x32_f16(as_half8(af2), as_half8(b2), acc1[t], 0, 0, 0);
    acc1[t] = __builtin_amdgcn_mfma_f32_16x16x32_f16(as_half8(af3), as_half8(b3), acc1[t], 0, 0, 0);
  }
#pragma unroll
  for (int t = 0; t < 8; ++t) {
#pragma unroll
    for (int r = 0; r < 4; ++r) {
      out[(size_t)(m0 + kb * 4 + r) * C + t * 16 + rc] = acc1[t][r];
    }
  }
}

extern "C" void kernel_launch(void* const* d_in, const int* in_sizes, int n_in,
                              void* d_out, int out_size, void* d_ws, size_t ws_size,
                              hipStream_t stream) {
  const float* x   = (const float*)d_in[0];
  const int*   ei  = (const int*)d_in[1];
  const float* gw  = (const float*)d_in[2];
  const float* gb  = (const float*)d_in[3];
  const float* bw0 = (const float*)d_in[4];
  const float* sw0 = (const float*)d_in[5];
  const float* sc0 = (const float*)d_in[6];
  const float* bw1 = (const float*)d_in[7];
  const float* sw1 = (const float*)d_in[8];
  const float* sc1 = (const float*)d_in[9];
  float* out = (float*)d_out;

  char* p = (char*)d_ws;
  u32* W16 = (u32*)p;         p += C * C * 2;
  u16* p0h = (u16*)p;         p += H * C * 8 * 2;
  u16* p1h = (u16*)p;         p += C * H * 8 * 2;
  float* dinv = (float*)p;    p += NN * 4;
  int* cnt = (int*)p;         p += NN * 4;
  int* excl = (int*)p;        p += NN * 4;
  int* bsums = (int*)p;       p += 256 * 4;
  int* row_start = (int*)p;   p += (NN + 4) * 4;
  int* slot = (int*)p;        p += (size_t)NE * 4;
  int* csr = (int*)p;         p += (size_t)NE * 4;
  u32* xs = (u32*)p;          p += (size_t)NN * C * 2;
  u32* ax16 = (u32*)p;        p += (size_t)NN * C * 2;
  __fp16* h16 = (__fp16*)p;   p += (size_t)NN * C * 2;

  const int* src = ei;
  const int* dst = ei + NE;

  hipMemsetAsync(cnt, 0, NN * 4, stream);

  prep_w<<<64, 256, 0, stream>>>(gw, bw0, sw0, sc0, bw1, sw1, sc1, W16, p0h, p1h);
  count_kernel<<<(NE + 255) / 256, 256, 0, stream>>>(dst, cnt, slot);
  scan1<<<196, 256, 0, stream>>>(cnt, excl, bsums, NN);
  scan3<<<196, 256, 0, stream>>>(excl, bsums, cnt, row_start, dinv, NN, 196);
  xs_prep<<<(NN * C / 4 + 255) / 256, 256, 0, stream>>>(x, dinv, xs);
  fill_kernel<<<(NE + 255) / 256, 256, 0, stream>>>(src, dst, slot, row_start, csr);
  agg_kernel<<<NN / 4, 256, 0, stream>>>(xs, csr, row_start, dinv, ax16);
  gemm_mfma<<<(NN + 63) / 64, 256, 0, stream>>>(ax16, W16, gb, h16);
  kan_mfma<<<(NN + 63) / 64, 256, 0, stream>>>(h16, p0h, p1h, out);
}

// Round 18
// 173.450 us; speedup vs baseline: 1.1807x; 1.0595x over previous
//
#include <hip/hip_runtime.h>

#define NN 50000
#define NE 800000
#define C 128
#define H 16

typedef unsigned int u32;
typedef unsigned short u16;
typedef __fp16 h2 __attribute__((ext_vector_type(2)));
typedef __fp16 half8 __attribute__((ext_vector_type(8)));
typedef float f32x4 __attribute__((ext_vector_type(4)));

__device__ __forceinline__ h2 as_h2(u32 v) {
  union { u32 u; h2 h; } c; c.u = v; return c.h;
}
__device__ __forceinline__ u32 as_u32(h2 h) {
  union { u32 u; h2 h; } c; c.h = h; return c.u;
}
__device__ __forceinline__ half8 as_half8(uint4 v) {
  union { uint4 u; half8 h; } c; c.u = v; return c.h;
}
#define PK(a, b) __builtin_amdgcn_cvt_pkrtz((a), (b))

// ---------- silu + 7 cubic B-spline bases, closed form, NAMED outputs ----------
__device__ __forceinline__ void feat8s(float x, float& s, float& g0, float& g1,
                                       float& g2, float& g3, float& g4, float& g5,
                                       float& g6) {
  s = x / (1.f + __expf(-x));
  float t = (x + 2.5f) * 2.0f;
  float cf = floorf(t);
  int c = (int)cf;
  float u = t - cf;
  float u2 = u * u, u3 = u2 * u;
  const float k6 = 1.f / 6.f;
  float P0 = u3 * k6;
  float P1 = (1.f + 3.f * u + 3.f * u2 - 3.f * u3) * k6;
  float P2 = (4.f - 6.f * u2 + 3.f * u3) * k6;
  float om = 1.f - u;
  float P3 = om * om * om * k6;
  bool valid = (t >= 0.f) && (t < 10.f);
#define SPJ(G, J)                                   \
  {                                                 \
    float b = 0.f;                                  \
    b = (c == (J)) ? P0 : b;                        \
    b = (c == (J) + 1) ? P1 : b;                    \
    b = (c == (J) + 2) ? P2 : b;                    \
    b = (c == (J) + 3) ? P3 : b;                    \
    G = valid ? b : 0.f;                            \
  }
  SPJ(g0, 0) SPJ(g1, 1) SPJ(g2, 2) SPJ(g3, 3) SPJ(g4, 4) SPJ(g5, 5) SPJ(g6, 6)
#undef SPJ
}

__device__ __forceinline__ u16 f2bf(float v) {
  u32 b = __float_as_uint(v);
  return (u16)((b + 0x7fffu + ((b >> 16) & 1u)) >> 16);  // RNE
}
__device__ __forceinline__ u16 f2h(float v) {
  union { __fp16 h; u16 u; } c; c.h = (__fp16)v; return c.u;
}
__device__ __forceinline__ float blo(u32 v) { return __uint_as_float(v << 16); }
__device__ __forceinline__ float bhi(u32 v) { return __uint_as_float(v & 0xffff0000u); }

// build a half8 A-fragment from one feat8s evaluation
__device__ __forceinline__ uint4 featfrag(float x) {
  float t0, t1, t2, t3, t4, t5, t6, t7;
  feat8s(x, t0, t1, t2, t3, t4, t5, t6, t7);
  uint4 r;
  r.x = as_u32(PK(t0, t1));
  r.y = as_u32(PK(t2, t3));
  r.z = as_u32(PK(t4, t5));
  r.w = as_u32(PK(t6, t7));
  return r;
}

// ---------- prep_w: f16 W + f16 KAN weights ----------
__global__ void prep_w(const float* __restrict__ W,
                       const float* __restrict__ bw0, const float* __restrict__ sw0,
                       const float* __restrict__ sc0,
                       const float* __restrict__ bw1, const float* __restrict__ sw1,
                       const float* __restrict__ sc1,
                       u32* __restrict__ W16, u16* __restrict__ p0h,
                       u16* __restrict__ p1h) {
  int i = blockIdx.x * blockDim.x + threadIdx.x;
  if (i < C * C / 2) {  // W row-major, packed f16 pairs along k
    int o = i >> 6, kp = i & 63;
    W16[i] = (u32)f2h(W[o * C + kp * 2]) | ((u32)f2h(W[o * C + kp * 2 + 1]) << 16);
  }
  if (i < H * C * 8) {  // p0h[hidden][k=f*8+j]
    int of = i >> 3, j = i & 7;
    float v = (j == 0) ? bw0[of] : sw0[of * 7 + (j - 1)] * sc0[of];
    p0h[i] = f2h(v);
  }
  if (i < C * H * 8) {  // p1h[out][k=j*8+t]
    int of = i >> 3, j = i & 7;
    float v = (j == 0) ? bw1[of] : sw1[of * 7 + (j - 1)] * sc1[of];
    p1h[i] = f2h(v);
  }
}

// ---------- count + slot capture ----------
__global__ void count_kernel(const int* __restrict__ dst, int* __restrict__ cnt,
                             int* __restrict__ slot) {
  int e = blockIdx.x * blockDim.x + threadIdx.x;
  if (e < NE) slot[e] = atomicAdd(&cnt[dst[e]], 1);
}

// ---------- scan1 ----------
__global__ void scan1(const int* __restrict__ cnt, int* __restrict__ excl,
                      int* __restrict__ bsums, int n) {
  int i = blockIdx.x * 256 + threadIdx.x;
  int v = (i < n) ? cnt[i] : 0;
  int lane = threadIdx.x & 63, wid = threadIdx.x >> 6;
  int s = v;
#pragma unroll
  for (int o = 1; o < 64; o <<= 1) {
    int t = __shfl_up(s, o, 64);
    if (lane >= o) s += t;
  }
  __shared__ int wsum[4];
  if (lane == 63) wsum[wid] = s;
  __syncthreads();
  int woff = 0;
  for (int w = 0; w < wid; ++w) woff += wsum[w];
  if (i < n) excl[i] = woff + s - v;
  if (threadIdx.x == 255) bsums[blockIdx.x] = woff + s;
}

// ---------- scan3 ----------
__global__ void scan3(const int* __restrict__ excl, const int* __restrict__ bsums,
                      const int* __restrict__ cnt, int* __restrict__ row_start,
                      float* __restrict__ dinv, int n, int nb) {
  __shared__ int red[256];
  const int t = threadIdx.x;
  red[t] = (t < nb && t < (int)blockIdx.x) ? bsums[t] : 0;
  __syncthreads();
#pragma unroll
  for (int s = 128; s > 0; s >>= 1) {
    if (t < s) red[t] += red[t + s];
    __syncthreads();
  }
  const int boff = red[0];
  const int i = blockIdx.x * 256 + t;
  if (i < n) {
    row_start[i] = excl[i] + boff;
    dinv[i] = rsqrtf((float)(cnt[i] + 1));
  }
  if (blockIdx.x == 0 && t == 0) row_start[n] = NE;
}

// ---------- xs_prep ----------
__global__ void xs_prep(const float* __restrict__ x, const float* __restrict__ dinv,
                        u32* __restrict__ xs) {
  int i = blockIdx.x * blockDim.x + threadIdx.x;
  if (i < NN * C / 4) {
    int n = i >> 5;
    float dv = dinv[n];
    float4 v = *(const float4*)&x[(size_t)i * 4];
    u32 lo = (u32)f2bf(v.x * dv) | ((u32)f2bf(v.y * dv) << 16);
    u32 hi = (u32)f2bf(v.z * dv) | ((u32)f2bf(v.w * dv) << 16);
    *(uint2*)&xs[(size_t)i * 2] = make_uint2(lo, hi);
  }
}

// ---------- CSR fill: atomic-free 2B scatter (node ids < 65536) ----------
__global__ void fill_kernel(const int* __restrict__ src, const int* __restrict__ dst,
                            const int* __restrict__ slot,
                            const int* __restrict__ row_start, u16* __restrict__ csr) {
  int e = blockIdx.x * blockDim.x + threadIdx.x;
  if (e < NE) csr[row_start[dst[e]] + slot[e]] = (u16)src[e];
}

// ---------- aggregation (u16 csr stream) ----------
__global__ __launch_bounds__(256, 8) void agg_kernel(
    const u32* __restrict__ xs, const u16* __restrict__ csr,
    const int* __restrict__ row_start, const float* __restrict__ dinv,
    u32* __restrict__ ax16) {
  const int l = threadIdx.x & 63;
  const int node = blockIdx.x * 4 + (threadIdx.x >> 6);
  const int e0 = row_start[node], e1 = row_start[node + 1];
  const float dn = dinv[node];
  const u32 vs = xs[(size_t)node * 64 + l];
  float a0 = blo(vs), a1 = bhi(vs);
  int e = e0;
  for (; e + 8 <= e1; e += 8) {
    const int s0 = csr[e], s1 = csr[e + 1], s2 = csr[e + 2], s3 = csr[e + 3];
    const int s4 = csr[e + 4], s5 = csr[e + 5], s6 = csr[e + 6], s7 = csr[e + 7];
    const u32 v0 = xs[(size_t)s0 * 64 + l];
    const u32 v1 = xs[(size_t)s1 * 64 + l];
    const u32 v2 = xs[(size_t)s2 * 64 + l];
    const u32 v3 = xs[(size_t)s3 * 64 + l];
    const u32 v4 = xs[(size_t)s4 * 64 + l];
    const u32 v5 = xs[(size_t)s5 * 64 + l];
    const u32 v6 = xs[(size_t)s6 * 64 + l];
    const u32 v7 = xs[(size_t)s7 * 64 + l];
    a0 += blo(v0); a1 += bhi(v0);
    a0 += blo(v1); a1 += bhi(v1);
    a0 += blo(v2); a1 += bhi(v2);
    a0 += blo(v3); a1 += bhi(v3);
    a0 += blo(v4); a1 += bhi(v4);
    a0 += blo(v5); a1 += bhi(v5);
    a0 += blo(v6); a1 += bhi(v6);
    a0 += blo(v7); a1 += bhi(v7);
  }
  for (; e < e1; ++e) {
    const u32 v = xs[(size_t)csr[e] * 64 + l];
    a0 += blo(v);
    a1 += bhi(v);
  }
  a0 *= dn;
  a1 *= dn;
  ax16[(size_t)node * 64 + l] = (u32)f2h(a0) | ((u32)f2h(a1) << 16);
}

// ---------- GEMM via MFMA f16, PERMUTED h16 output ----------
// col c stored at p = (c&3)*32 + (c>>2)  (class-major), so kan_mfma's lane
// (rc,kb) reads its 32 K0 inputs (f = s*4+kb) contiguously at [kb*32 .. +31].
__global__ __launch_bounds__(256) void gemm_mfma(const u32* __restrict__ ax16,
                                                 const u32* __restrict__ W16,
                                                 const float* __restrict__ bias,
                                                 __fp16* __restrict__ h16p) {
  const int wv = threadIdx.x >> 6;
  const int l = threadIdx.x & 63;
  const int m0 = (blockIdx.x * 4 + wv) * 16;
  if (m0 >= NN) return;
  const int rc = l & 15, kb = l >> 4;
  uint4 a[4];
#pragma unroll
  for (int s = 0; s < 4; ++s)
    a[s] = *(const uint4*)&ax16[(size_t)(m0 + rc) * 64 + s * 16 + kb * 4];
  f32x4 acc[8];
#pragma unroll
  for (int t = 0; t < 8; ++t) acc[t] = (f32x4){0.f, 0.f, 0.f, 0.f};
#pragma unroll
  for (int t = 0; t < 8; ++t) {
#pragma unroll
    for (int s = 0; s < 4; ++s) {
      uint4 b = *(const uint4*)&W16[(size_t)(t * 16 + rc) * 64 + s * 16 + kb * 4];
      acc[t] = __builtin_amdgcn_mfma_f32_16x16x32_f16(as_half8(a[s]), as_half8(b),
                                                      acc[t], 0, 0, 0);
    }
  }
  const int pbase = (rc & 3) * 32 + (rc >> 2);  // permuted col for t=0
#pragma unroll
  for (int t = 0; t < 8; ++t) {
    const float bo = bias[t * 16 + rc];
#pragma unroll
    for (int r = 0; r < 4; ++r) {
      h16p[(size_t)(m0 + kb * 4 + r) * C + pbase + t * 4] = (__fp16)(acc[t][r] + bo);
    }
  }
}

// ---------- kan_mfma: both KAN layers on the matrix pipe ----------
// (256,3): allow 128 VGPR so the 32 independent featfrag chains + loads can
// interleave (r17: default 48 VGPR serialized them -> 29% VALUBusy, latency-bound).
__global__ __launch_bounds__(256, 3) void kan_mfma(
    const __fp16* __restrict__ h16p, const u16* __restrict__ p0h,
    const u16* __restrict__ p1h, float* __restrict__ out) {
  __shared__ float hidT[4][16][17];
  const int wv = threadIdx.x >> 6;
  const int l = threadIdx.x & 63;
  const int m0 = (blockIdx.x * 4 + wv) * 16;
  if (m0 >= NN) return;
  const int rc = l & 15, kb = l >> 4;
  // ---- K0: 4 vector loads cover the lane's 32 inputs (permuted layout) ----
  const __fp16* hrow = &h16p[(size_t)(m0 + rc) * C + kb * 32];
  u32 hw[16];
  *(uint4*)&hw[0] = ((const uint4*)hrow)[0];
  *(uint4*)&hw[4] = ((const uint4*)hrow)[1];
  *(uint4*)&hw[8] = ((const uint4*)hrow)[2];
  *(uint4*)&hw[12] = ((const uint4*)hrow)[3];
  f32x4 acc0 = (f32x4){0.f, 0.f, 0.f, 0.f};
#pragma unroll
  for (int s = 0; s < 32; ++s) {
    u32 w = hw[s >> 1];  // static after unroll
    float xv = (float)((s & 1) ? as_h2(w)[1] : as_h2(w)[0]);
    uint4 au = featfrag(xv);
    uint4 bu = *(const uint4*)&p0h[rc * 1024 + s * 32 + kb * 8];
    acc0 = __builtin_amdgcn_mfma_f32_16x16x32_f16(as_half8(au), as_half8(bu),
                                                  acc0, 0, 0, 0);
  }
  // ---- transpose hid within the wave via LDS ----
#pragma unroll
  for (int r = 0; r < 4; ++r) hidT[wv][kb * 4 + r][rc] = acc0[r];
  __builtin_amdgcn_s_waitcnt(0);  // lgkmcnt(0): wave-local LDS ordering
  // ---- K1 A-fragments: feat8s of hid[node rc][hidden s*4+kb] ----
  uint4 af0 = featfrag(hidT[wv][rc][0 * 4 + kb]);
  uint4 af1 = featfrag(hidT[wv][rc][1 * 4 + kb]);
  uint4 af2 = featfrag(hidT[wv][rc][2 * 4 + kb]);
  uint4 af3 = featfrag(hidT[wv][rc][3 * 4 + kb]);
  // ---- K1: 8 output tiles x 4 k-steps ----
  f32x4 acc1[8];
#pragma unroll
  for (int t = 0; t < 8; ++t) acc1[t] = (f32x4){0.f, 0.f, 0.f, 0.f};
#pragma unroll
  for (int t = 0; t < 8; ++t) {
    const u16* prow = &p1h[(size_t)(t * 16 + rc) * 128];
    uint4 b0 = *(const uint4*)&prow[0 * 32 + kb * 8];
    uint4 b1 = *(const uint4*)&prow[1 * 32 + kb * 8];
    uint4 b2 = *(const uint4*)&prow[2 * 32 + kb * 8];
    uint4 b3 = *(const uint4*)&prow[3 * 32 + kb * 8];
    acc1[t] = __builtin_amdgcn_mfma_f32_16x16x32_f16(as_half8(af0), as_half8(b0), acc1[t], 0, 0, 0);
    acc1[t] = __builtin_amdgcn_mfma_f32_16x16x32_f16(as_half8(af1), as_half8(b1), acc1[t], 0, 0, 0);
    acc1[t] = __builtin_amdgcn_mfma_f32_16x16x32_f16(as_half8(af2), as_half8(b2), acc1[t], 0, 0, 0);
    acc1[t] = __builtin_amdgcn_mfma_f32_16x16x32_f16(as_half8(af3), as_half8(b3), acc1[t], 0, 0, 0);
  }
#pragma unroll
  for (int t = 0; t < 8; ++t) {
#pragma unroll
    for (int r = 0; r < 4; ++r) {
      out[(size_t)(m0 + kb * 4 + r) * C + t * 16 + rc] = acc1[t][r];
    }
  }
}

extern "C" void kernel_launch(void* const* d_in, const int* in_sizes, int n_in,
                              void* d_out, int out_size, void* d_ws, size_t ws_size,
                              hipStream_t stream) {
  const float* x   = (const float*)d_in[0];
  const int*   ei  = (const int*)d_in[1];
  const float* gw  = (const float*)d_in[2];
  const float* gb  = (const float*)d_in[3];
  const float* bw0 = (const float*)d_in[4];
  const float* sw0 = (const float*)d_in[5];
  const float* sc0 = (const float*)d_in[6];
  const float* bw1 = (const float*)d_in[7];
  const float* sw1 = (const float*)d_in[8];
  const float* sc1 = (const float*)d_in[9];
  float* out = (float*)d_out;

  char* p = (char*)d_ws;
  u32* W16 = (u32*)p;         p += C * C * 2;
  u16* p0h = (u16*)p;         p += H * C * 8 * 2;
  u16* p1h = (u16*)p;         p += C * H * 8 * 2;
  float* dinv = (float*)p;    p += NN * 4;
  int* cnt = (int*)p;         p += NN * 4;
  int* excl = (int*)p;        p += NN * 4;
  int* bsums = (int*)p;       p += 256 * 4;
  int* row_start = (int*)p;   p += (NN + 4) * 4;
  int* slot = (int*)p;        p += (size_t)NE * 4;       // 3.2 MB
  u16* csr = (u16*)p;         p += (size_t)NE * 2;       // 1.6 MB
  p = (char*)(((size_t)p + 15) & ~(size_t)15);
  u32* xs = (u32*)p;          p += (size_t)NN * C * 2;   // 12.8 MB
  u32* ax16 = (u32*)p;        p += (size_t)NN * C * 2;   // 12.8 MB
  __fp16* h16p = (__fp16*)p;  p += (size_t)NN * C * 2;   // 12.8 MB

  const int* src = ei;
  const int* dst = ei + NE;

  hipMemsetAsync(cnt, 0, NN * 4, stream);

  prep_w<<<64, 256, 0, stream>>>(gw, bw0, sw0, sc0, bw1, sw1, sc1, W16, p0h, p1h);
  count_kernel<<<(NE + 255) / 256, 256, 0, stream>>>(dst, cnt, slot);
  scan1<<<196, 256, 0, stream>>>(cnt, excl, bsums, NN);
  scan3<<<196, 256, 0, stream>>>(excl, bsums, cnt, row_start, dinv, NN, 196);
  xs_prep<<<(NN * C / 4 + 255) / 256, 256, 0, stream>>>(x, dinv, xs);
  fill_kernel<<<(NE + 255) / 256, 256, 0, stream>>>(src, dst, slot, row_start, csr);
  agg_kernel<<<NN / 4, 256, 0, stream>>>(xs, csr, row_start, dinv, ax16);
  gemm_mfma<<<(NN + 63) / 64, 256, 0, stream>>>(ax16, W16, gb, h16p);
  kan_mfma<<<(NN + 63) / 64, 256, 0, stream>>>(h16p, p0h, p1h, out);
}

// Round 19
// 159.741 us; speedup vs baseline: 1.2820x; 1.0858x over previous
//
#include <hip/hip_runtime.h>

#define NN 50000
#define NE 800000
#define C 128
#define H 16

typedef unsigned int u32;
typedef unsigned short u16;
typedef __fp16 h2 __attribute__((ext_vector_type(2)));
typedef __fp16 half8 __attribute__((ext_vector_type(8)));
typedef float f32x4 __attribute__((ext_vector_type(4)));

__device__ __forceinline__ h2 as_h2(u32 v) {
  union { u32 u; h2 h; } c; c.u = v; return c.h;
}
__device__ __forceinline__ u32 as_u32(h2 h) {
  union { u32 u; h2 h; } c; c.h = h; return c.u;
}
__device__ __forceinline__ half8 as_half8(uint4 v) {
  union { uint4 u; half8 h; } c; c.u = v; return c.h;
}
#define PK(a, b) __builtin_amdgcn_cvt_pkrtz((a), (b))

// ---------- silu + 7 cubic B-spline bases, closed form, NAMED outputs ----------
__device__ __forceinline__ void feat8s(float x, float& s, float& g0, float& g1,
                                       float& g2, float& g3, float& g4, float& g5,
                                       float& g6) {
  s = x / (1.f + __expf(-x));
  float t = (x + 2.5f) * 2.0f;
  float cf = floorf(t);
  int c = (int)cf;
  float u = t - cf;
  float u2 = u * u, u3 = u2 * u;
  const float k6 = 1.f / 6.f;
  float P0 = u3 * k6;
  float P1 = (1.f + 3.f * u + 3.f * u2 - 3.f * u3) * k6;
  float P2 = (4.f - 6.f * u2 + 3.f * u3) * k6;
  float om = 1.f - u;
  float P3 = om * om * om * k6;
  bool valid = (t >= 0.f) && (t < 10.f);
#define SPJ(G, J)                                   \
  {                                                 \
    float b = 0.f;                                  \
    b = (c == (J)) ? P0 : b;                        \
    b = (c == (J) + 1) ? P1 : b;                    \
    b = (c == (J) + 2) ? P2 : b;                    \
    b = (c == (J) + 3) ? P3 : b;                    \
    G = valid ? b : 0.f;                            \
  }
  SPJ(g0, 0) SPJ(g1, 1) SPJ(g2, 2) SPJ(g3, 3) SPJ(g4, 4) SPJ(g5, 5) SPJ(g6, 6)
#undef SPJ
}

__device__ __forceinline__ u16 f2bf(float v) {
  u32 b = __float_as_uint(v);
  return (u16)((b + 0x7fffu + ((b >> 16) & 1u)) >> 16);  // RNE
}
__device__ __forceinline__ u16 f2h(float v) {
  union { __fp16 h; u16 u; } c; c.h = (__fp16)v; return c.u;
}
__device__ __forceinline__ float blo(u32 v) { return __uint_as_float(v << 16); }
__device__ __forceinline__ float bhi(u32 v) { return __uint_as_float(v & 0xffff0000u); }

// build a half8 A-fragment from one feat8s evaluation
__device__ __forceinline__ uint4 featfrag(float x) {
  float t0, t1, t2, t3, t4, t5, t6, t7;
  feat8s(x, t0, t1, t2, t3, t4, t5, t6, t7);
  uint4 r;
  r.x = as_u32(PK(t0, t1));
  r.y = as_u32(PK(t2, t3));
  r.z = as_u32(PK(t4, t5));
  r.w = as_u32(PK(t6, t7));
  return r;
}

// ---------- prep_w: f16 W + f16 KAN weights + zero cnt (196 blocks) ----------
__global__ void prep_w(const float* __restrict__ W,
                       const float* __restrict__ bw0, const float* __restrict__ sw0,
                       const float* __restrict__ sc0,
                       const float* __restrict__ bw1, const float* __restrict__ sw1,
                       const float* __restrict__ sc1,
                       u32* __restrict__ W16, u16* __restrict__ p0h,
                       u16* __restrict__ p1h, int* __restrict__ cnt) {
  int i = blockIdx.x * blockDim.x + threadIdx.x;
  if (i < NN) cnt[i] = 0;
  if (i < C * C / 2) {  // W row-major, packed f16 pairs along k
    int o = i >> 6, kp = i & 63;
    W16[i] = (u32)f2h(W[o * C + kp * 2]) | ((u32)f2h(W[o * C + kp * 2 + 1]) << 16);
  }
  if (i < H * C * 8) {  // p0h[hidden][k=f*8+j]
    int of = i >> 3, j = i & 7;
    float v = (j == 0) ? bw0[of] : sw0[of * 7 + (j - 1)] * sc0[of];
    p0h[i] = f2h(v);
  }
  if (i < C * H * 8) {  // p1h[out][k=j*8+t]
    int of = i >> 3, j = i & 7;
    float v = (j == 0) ? bw1[of] : sw1[of * 7 + (j - 1)] * sc1[of];
    p1h[i] = f2h(v);
  }
}

// ---------- count + slot capture (u16 slots: max degree << 65536) ----------
__global__ void count_kernel(const int* __restrict__ dst, int* __restrict__ cnt,
                             u16* __restrict__ slot) {
  int e = blockIdx.x * blockDim.x + threadIdx.x;
  if (e < NE) slot[e] = (u16)atomicAdd(&cnt[dst[e]], 1);
}

// ---------- scan1 ----------
__global__ void scan1(const int* __restrict__ cnt, int* __restrict__ excl,
                      int* __restrict__ bsums, int n) {
  int i = blockIdx.x * 256 + threadIdx.x;
  int v = (i < n) ? cnt[i] : 0;
  int lane = threadIdx.x & 63, wid = threadIdx.x >> 6;
  int s = v;
#pragma unroll
  for (int o = 1; o < 64; o <<= 1) {
    int t = __shfl_up(s, o, 64);
    if (lane >= o) s += t;
  }
  __shared__ int wsum[4];
  if (lane == 63) wsum[wid] = s;
  __syncthreads();
  int woff = 0;
  for (int w = 0; w < wid; ++w) woff += wsum[w];
  if (i < n) excl[i] = woff + s - v;
  if (threadIdx.x == 255) bsums[blockIdx.x] = woff + s;
}

// ---------- scan3 ----------
__global__ void scan3(const int* __restrict__ excl, const int* __restrict__ bsums,
                      const int* __restrict__ cnt, int* __restrict__ row_start,
                      float* __restrict__ dinv, int n, int nb) {
  __shared__ int red[256];
  const int t = threadIdx.x;
  red[t] = (t < nb && t < (int)blockIdx.x) ? bsums[t] : 0;
  __syncthreads();
#pragma unroll
  for (int s = 128; s > 0; s >>= 1) {
    if (t < s) red[t] += red[t + s];
    __syncthreads();
  }
  const int boff = red[0];
  const int i = blockIdx.x * 256 + t;
  if (i < n) {
    row_start[i] = excl[i] + boff;
    dinv[i] = rsqrtf((float)(cnt[i] + 1));
  }
  if (blockIdx.x == 0 && t == 0) row_start[n] = NE;
}

// ---------- xs_prep ----------
__global__ void xs_prep(const float* __restrict__ x, const float* __restrict__ dinv,
                        u32* __restrict__ xs) {
  int i = blockIdx.x * blockDim.x + threadIdx.x;
  if (i < NN * C / 4) {
    int n = i >> 5;
    float dv = dinv[n];
    float4 v = *(const float4*)&x[(size_t)i * 4];
    u32 lo = (u32)f2bf(v.x * dv) | ((u32)f2bf(v.y * dv) << 16);
    u32 hi = (u32)f2bf(v.z * dv) | ((u32)f2bf(v.w * dv) << 16);
    *(uint2*)&xs[(size_t)i * 2] = make_uint2(lo, hi);
  }
}

// ---------- CSR fill: atomic-free 2B scatter ----------
__global__ void fill_kernel(const int* __restrict__ src, const int* __restrict__ dst,
                            const u16* __restrict__ slot,
                            const int* __restrict__ row_start, u16* __restrict__ csr) {
  int e = blockIdx.x * blockDim.x + threadIdx.x;
  if (e < NE) csr[row_start[dst[e]] + (int)slot[e]] = (u16)src[e];
}

// ---------- aggregation (u16 csr stream) ----------
__global__ __launch_bounds__(256, 8) void agg_kernel(
    const u32* __restrict__ xs, const u16* __restrict__ csr,
    const int* __restrict__ row_start, const float* __restrict__ dinv,
    u32* __restrict__ ax16) {
  const int l = threadIdx.x & 63;
  const int node = blockIdx.x * 4 + (threadIdx.x >> 6);
  const int e0 = row_start[node], e1 = row_start[node + 1];
  const float dn = dinv[node];
  const u32 vs = xs[(size_t)node * 64 + l];
  float a0 = blo(vs), a1 = bhi(vs);
  int e = e0;
  for (; e + 8 <= e1; e += 8) {
    const int s0 = csr[e], s1 = csr[e + 1], s2 = csr[e + 2], s3 = csr[e + 3];
    const int s4 = csr[e + 4], s5 = csr[e + 5], s6 = csr[e + 6], s7 = csr[e + 7];
    const u32 v0 = xs[(size_t)s0 * 64 + l];
    const u32 v1 = xs[(size_t)s1 * 64 + l];
    const u32 v2 = xs[(size_t)s2 * 64 + l];
    const u32 v3 = xs[(size_t)s3 * 64 + l];
    const u32 v4 = xs[(size_t)s4 * 64 + l];
    const u32 v5 = xs[(size_t)s5 * 64 + l];
    const u32 v6 = xs[(size_t)s6 * 64 + l];
    const u32 v7 = xs[(size_t)s7 * 64 + l];
    a0 += blo(v0); a1 += bhi(v0);
    a0 += blo(v1); a1 += bhi(v1);
    a0 += blo(v2); a1 += bhi(v2);
    a0 += blo(v3); a1 += bhi(v3);
    a0 += blo(v4); a1 += bhi(v4);
    a0 += blo(v5); a1 += bhi(v5);
    a0 += blo(v6); a1 += bhi(v6);
    a0 += blo(v7); a1 += bhi(v7);
  }
  for (; e < e1; ++e) {
    const u32 v = xs[(size_t)csr[e] * 64 + l];
    a0 += blo(v);
    a1 += bhi(v);
  }
  a0 *= dn;
  a1 *= dn;
  ax16[(size_t)node * 64 + l] = (u32)f2h(a0) | ((u32)f2h(a1) << 16);
}

// ---------- gemmkan: GCN GEMM + both KAN layers, fused via per-wave LDS tile ----------
// Phase A: h = ax @ W^T + bias (32 MFMA, D layout col=l&15,row=(l>>4)*4+r) ->
//   LDS hT[node-local][col] (f32, 2-way conflicts only).
// Phase C (K0): lane (rc,kb) reads hT[rc][s*4+kb], feat8s -> A-frag; 32 MFMA.
// transpose hid via hidT; K1: 8x4 MFMA -> out. All wave-local (s_waitcnt only).
__global__ __launch_bounds__(256, 3) void gemmkan(
    const u32* __restrict__ ax16, const u32* __restrict__ W16,
    const float* __restrict__ bias, const u16* __restrict__ p0h,
    const u16* __restrict__ p1h, float* __restrict__ out) {
  __shared__ float hT[4][16][132];
  __shared__ float hidT[4][16][17];
  const int wv = threadIdx.x >> 6;
  const int l = threadIdx.x & 63;
  const int m0 = (blockIdx.x * 4 + wv) * 16;
  if (m0 >= NN) return;
  const int rc = l & 15, kb = l >> 4;
  // ---- Phase A: GCN GEMM ----
  {
    uint4 a[4];
#pragma unroll
    for (int s = 0; s < 4; ++s)
      a[s] = *(const uint4*)&ax16[(size_t)(m0 + rc) * 64 + s * 16 + kb * 4];
    f32x4 acc[8];
#pragma unroll
    for (int t = 0; t < 8; ++t) acc[t] = (f32x4){0.f, 0.f, 0.f, 0.f};
#pragma unroll
    for (int t = 0; t < 8; ++t) {
#pragma unroll
      for (int s = 0; s < 4; ++s) {
        uint4 b = *(const uint4*)&W16[(size_t)(t * 16 + rc) * 64 + s * 16 + kb * 4];
        acc[t] = __builtin_amdgcn_mfma_f32_16x16x32_f16(as_half8(a[s]), as_half8(b),
                                                        acc[t], 0, 0, 0);
      }
    }
#pragma unroll
    for (int t = 0; t < 8; ++t) {
      const float bo = bias[t * 16 + rc];
#pragma unroll
      for (int r = 0; r < 4; ++r) {
        hT[wv][kb * 4 + r][t * 16 + rc] = acc[t][r] + bo;
      }
    }
  }
  __builtin_amdgcn_s_waitcnt(0);  // wave-local LDS ordering (r17-proven)
  // ---- Phase C: K0 on matrix pipe ----
  f32x4 acc0 = (f32x4){0.f, 0.f, 0.f, 0.f};
#pragma unroll
  for (int s = 0; s < 32; ++s) {
    uint4 au = featfrag(hT[wv][rc][s * 4 + kb]);
    uint4 bu = *(const uint4*)&p0h[rc * 1024 + s * 32 + kb * 8];
    acc0 = __builtin_amdgcn_mfma_f32_16x16x32_f16(as_half8(au), as_half8(bu),
                                                  acc0, 0, 0, 0);
  }
  // ---- transpose hid within the wave ----
#pragma unroll
  for (int r = 0; r < 4; ++r) hidT[wv][kb * 4 + r][rc] = acc0[r];
  __builtin_amdgcn_s_waitcnt(0);
  // ---- K1 A-fragments ----
  uint4 af0 = featfrag(hidT[wv][rc][0 * 4 + kb]);
  uint4 af1 = featfrag(hidT[wv][rc][1 * 4 + kb]);
  uint4 af2 = featfrag(hidT[wv][rc][2 * 4 + kb]);
  uint4 af3 = featfrag(hidT[wv][rc][3 * 4 + kb]);
  // ---- K1: 8 output tiles x 4 k-steps ----
  f32x4 acc1[8];
#pragma unroll
  for (int t = 0; t < 8; ++t) acc1[t] = (f32x4){0.f, 0.f, 0.f, 0.f};
#pragma unroll
  for (int t = 0; t < 8; ++t) {
    const u16* prow = &p1h[(size_t)(t * 16 + rc) * 128];
    uint4 b0 = *(const uint4*)&prow[0 * 32 + kb * 8];
    uint4 b1 = *(const uint4*)&prow[1 * 32 + kb * 8];
    uint4 b2 = *(const uint4*)&prow[2 * 32 + kb * 8];
    uint4 b3 = *(const uint4*)&prow[3 * 32 + kb * 8];
    acc1[t] = __builtin_amdgcn_mfma_f32_16x16x32_f16(as_half8(af0), as_half8(b0), acc1[t], 0, 0, 0);
    acc1[t] = __builtin_amdgcn_mfma_f32_16x16x32_f16(as_half8(af1), as_half8(b1), acc1[t], 0, 0, 0);
    acc1[t] = __builtin_amdgcn_mfma_f32_16x16x32_f16(as_half8(af2), as_half8(b2), acc1[t], 0, 0, 0);
    acc1[t] = __builtin_amdgcn_mfma_f32_16x16x32_f16(as_half8(af3), as_half8(b3), acc1[t], 0, 0, 0);
  }
#pragma unroll
  for (int t = 0; t < 8; ++t) {
#pragma unroll
    for (int r = 0; r < 4; ++r) {
      out[(size_t)(m0 + kb * 4 + r) * C + t * 16 + rc] = acc1[t][r];
    }
  }
}

extern "C" void kernel_launch(void* const* d_in, const int* in_sizes, int n_in,
                              void* d_out, int out_size, void* d_ws, size_t ws_size,
                              hipStream_t stream) {
  const float* x   = (const float*)d_in[0];
  const int*   ei  = (const int*)d_in[1];
  const float* gw  = (const float*)d_in[2];
  const float* gb  = (const float*)d_in[3];
  const float* bw0 = (const float*)d_in[4];
  const float* sw0 = (const float*)d_in[5];
  const float* sc0 = (const float*)d_in[6];
  const float* bw1 = (const float*)d_in[7];
  const float* sw1 = (const float*)d_in[8];
  const float* sc1 = (const float*)d_in[9];
  float* out = (float*)d_out;

  char* p = (char*)d_ws;
  u32* W16 = (u32*)p;         p += C * C * 2;
  u16* p0h = (u16*)p;         p += H * C * 8 * 2;
  u16* p1h = (u16*)p;         p += C * H * 8 * 2;
  float* dinv = (float*)p;    p += NN * 4;
  int* cnt = (int*)p;         p += NN * 4;
  int* excl = (int*)p;        p += NN * 4;
  int* bsums = (int*)p;       p += 256 * 4;
  int* row_start = (int*)p;   p += (NN + 4) * 4;
  u16* slot = (u16*)p;        p += (size_t)NE * 2;       // 1.6 MB
  u16* csr = (u16*)p;         p += (size_t)NE * 2;       // 1.6 MB
  p = (char*)(((size_t)p + 15) & ~(size_t)15);
  u32* xs = (u32*)p;          p += (size_t)NN * C * 2;   // 12.8 MB
  u32* ax16 = (u32*)p;        p += (size_t)NN * C * 2;   // 12.8 MB

  const int* src = ei;
  const int* dst = ei + NE;

  prep_w<<<196, 256, 0, stream>>>(gw, bw0, sw0, sc0, bw1, sw1, sc1, W16, p0h, p1h, cnt);
  count_kernel<<<(NE + 255) / 256, 256, 0, stream>>>(dst, cnt, slot);
  scan1<<<196, 256, 0, stream>>>(cnt, excl, bsums, NN);
  scan3<<<196, 256, 0, stream>>>(excl, bsums, cnt, row_start, dinv, NN, 196);
  xs_prep<<<(NN * C / 4 + 255) / 256, 256, 0, stream>>>(x, dinv, xs);
  fill_kernel<<<(NE + 255) / 256, 256, 0, stream>>>(src, dst, slot, row_start, csr);
  agg_kernel<<<NN / 4, 256, 0, stream>>>(xs, csr, row_start, dinv, ax16);
  gemmkan<<<(NN + 63) / 64, 256, 0, stream>>>(ax16, W16, gb, p0h, p1h, out);
}

// Round 20
// 159.445 us; speedup vs baseline: 1.2844x; 1.0019x over previous
//
#include <hip/hip_runtime.h>

#define NN 50000
#define NE 800000
#define C 128
#define H 16

typedef unsigned int u32;
typedef unsigned short u16;
typedef __fp16 h2 __attribute__((ext_vector_type(2)));
typedef __fp16 half8 __attribute__((ext_vector_type(8)));
typedef float f32x4 __attribute__((ext_vector_type(4)));

__device__ __forceinline__ h2 as_h2(u32 v) {
  union { u32 u; h2 h; } c; c.u = v; return c.h;
}
__device__ __forceinline__ u32 as_u32(h2 h) {
  union { u32 u; h2 h; } c; c.h = h; return c.u;
}
__device__ __forceinline__ half8 as_half8(uint4 v) {
  union { uint4 u; half8 h; } c; c.u = v; return c.h;
}
#define PK(a, b) __builtin_amdgcn_cvt_pkrtz((a), (b))

// ---------- silu + 7 cubic B-spline bases, closed form, NAMED outputs ----------
__device__ __forceinline__ void feat8s(float x, float& s, float& g0, float& g1,
                                       float& g2, float& g3, float& g4, float& g5,
                                       float& g6) {
  s = x / (1.f + __expf(-x));
  float t = (x + 2.5f) * 2.0f;
  float cf = floorf(t);
  int c = (int)cf;
  float u = t - cf;
  float u2 = u * u, u3 = u2 * u;
  const float k6 = 1.f / 6.f;
  float P0 = u3 * k6;
  float P1 = (1.f + 3.f * u + 3.f * u2 - 3.f * u3) * k6;
  float P2 = (4.f - 6.f * u2 + 3.f * u3) * k6;
  float om = 1.f - u;
  float P3 = om * om * om * k6;
  bool valid = (t >= 0.f) && (t < 10.f);
#define SPJ(G, J)                                   \
  {                                                 \
    float b = 0.f;                                  \
    b = (c == (J)) ? P0 : b;                        \
    b = (c == (J) + 1) ? P1 : b;                    \
    b = (c == (J) + 2) ? P2 : b;                    \
    b = (c == (J) + 3) ? P3 : b;                    \
    G = valid ? b : 0.f;                            \
  }
  SPJ(g0, 0) SPJ(g1, 1) SPJ(g2, 2) SPJ(g3, 3) SPJ(g4, 4) SPJ(g5, 5) SPJ(g6, 6)
#undef SPJ
}

__device__ __forceinline__ u16 f2bf(float v) {
  u32 b = __float_as_uint(v);
  return (u16)((b + 0x7fffu + ((b >> 16) & 1u)) >> 16);  // RNE
}
__device__ __forceinline__ u16 f2h(float v) {
  union { __fp16 h; u16 u; } c; c.h = (__fp16)v; return c.u;
}
__device__ __forceinline__ float blo(u32 v) { return __uint_as_float(v << 16); }
__device__ __forceinline__ float bhi(u32 v) { return __uint_as_float(v & 0xffff0000u); }

// build a half8 A-fragment from one feat8s evaluation
__device__ __forceinline__ uint4 featfrag(float x) {
  float t0, t1, t2, t3, t4, t5, t6, t7;
  feat8s(x, t0, t1, t2, t3, t4, t5, t6, t7);
  uint4 r;
  r.x = as_u32(PK(t0, t1));
  r.y = as_u32(PK(t2, t3));
  r.z = as_u32(PK(t4, t5));
  r.w = as_u32(PK(t6, t7));
  return r;
}

// ---------- prep_w: f16 W + f16 KAN weights + zero cnt (196 blocks) ----------
__global__ void prep_w(const float* __restrict__ W,
                       const float* __restrict__ bw0, const float* __restrict__ sw0,
                       const float* __restrict__ sc0,
                       const float* __restrict__ bw1, const float* __restrict__ sw1,
                       const float* __restrict__ sc1,
                       u32* __restrict__ W16, u16* __restrict__ p0h,
                       u16* __restrict__ p1h, int* __restrict__ cnt) {
  int i = blockIdx.x * blockDim.x + threadIdx.x;
  if (i < NN) cnt[i] = 0;
  if (i < C * C / 2) {  // W row-major, packed f16 pairs along k
    int o = i >> 6, kp = i & 63;
    W16[i] = (u32)f2h(W[o * C + kp * 2]) | ((u32)f2h(W[o * C + kp * 2 + 1]) << 16);
  }
  if (i < H * C * 8) {  // p0h[hidden][k=f*8+j]
    int of = i >> 3, j = i & 7;
    float v = (j == 0) ? bw0[of] : sw0[of * 7 + (j - 1)] * sc0[of];
    p0h[i] = f2h(v);
  }
  if (i < C * H * 8) {  // p1h[out][k=j*8+t]
    int of = i >> 3, j = i & 7;
    float v = (j == 0) ? bw1[of] : sw1[of * 7 + (j - 1)] * sc1[of];
    p1h[i] = f2h(v);
  }
}

// ---------- count + slot capture (u16 slots) ----------
__global__ void count_kernel(const int* __restrict__ dst, int* __restrict__ cnt,
                             u16* __restrict__ slot) {
  int e = blockIdx.x * blockDim.x + threadIdx.x;
  if (e < NE) slot[e] = (u16)atomicAdd(&cnt[dst[e]], 1);
}

// ---------- scan1 ----------
__global__ void scan1(const int* __restrict__ cnt, int* __restrict__ excl,
                      int* __restrict__ bsums, int n) {
  int i = blockIdx.x * 256 + threadIdx.x;
  int v = (i < n) ? cnt[i] : 0;
  int lane = threadIdx.x & 63, wid = threadIdx.x >> 6;
  int s = v;
#pragma unroll
  for (int o = 1; o < 64; o <<= 1) {
    int t = __shfl_up(s, o, 64);
    if (lane >= o) s += t;
  }
  __shared__ int wsum[4];
  if (lane == 63) wsum[wid] = s;
  __syncthreads();
  int woff = 0;
  for (int w = 0; w < wid; ++w) woff += wsum[w];
  if (i < n) excl[i] = woff + s - v;
  if (threadIdx.x == 255) bsums[blockIdx.x] = woff + s;
}

// ---------- scan3 ----------
__global__ void scan3(const int* __restrict__ excl, const int* __restrict__ bsums,
                      const int* __restrict__ cnt, int* __restrict__ row_start,
                      float* __restrict__ dinv, int n, int nb) {
  __shared__ int red[256];
  const int t = threadIdx.x;
  red[t] = (t < nb && t < (int)blockIdx.x) ? bsums[t] : 0;
  __syncthreads();
#pragma unroll
  for (int s = 128; s > 0; s >>= 1) {
    if (t < s) red[t] += red[t + s];
    __syncthreads();
  }
  const int boff = red[0];
  const int i = blockIdx.x * 256 + t;
  if (i < n) {
    row_start[i] = excl[i] + boff;
    dinv[i] = rsqrtf((float)(cnt[i] + 1));
  }
  if (blockIdx.x == 0 && t == 0) row_start[n] = NE;
}

// ---------- xs_prep ----------
__global__ void xs_prep(const float* __restrict__ x, const float* __restrict__ dinv,
                        u32* __restrict__ xs) {
  int i = blockIdx.x * blockDim.x + threadIdx.x;
  if (i < NN * C / 4) {
    int n = i >> 5;
    float dv = dinv[n];
    float4 v = *(const float4*)&x[(size_t)i * 4];
    u32 lo = (u32)f2bf(v.x * dv) | ((u32)f2bf(v.y * dv) << 16);
    u32 hi = (u32)f2bf(v.z * dv) | ((u32)f2bf(v.w * dv) << 16);
    *(uint2*)&xs[(size_t)i * 2] = make_uint2(lo, hi);
  }
}

// ---------- CSR fill: atomic-free 2B scatter ----------
__global__ void fill_kernel(const int* __restrict__ src, const int* __restrict__ dst,
                            const u16* __restrict__ slot,
                            const int* __restrict__ row_start, u16* __restrict__ csr) {
  int e = blockIdx.x * blockDim.x + threadIdx.x;
  if (e < NE) csr[row_start[dst[e]] + (int)slot[e]] = (u16)src[e];
}

// ---------- aggregation (u16 csr stream) ----------
__global__ __launch_bounds__(256, 8) void agg_kernel(
    const u32* __restrict__ xs, const u16* __restrict__ csr,
    const int* __restrict__ row_start, const float* __restrict__ dinv,
    u32* __restrict__ ax16) {
  const int l = threadIdx.x & 63;
  const int node = blockIdx.x * 4 + (threadIdx.x >> 6);
  const int e0 = row_start[node], e1 = row_start[node + 1];
  const float dn = dinv[node];
  const u32 vs = xs[(size_t)node * 64 + l];
  float a0 = blo(vs), a1 = bhi(vs);
  int e = e0;
  for (; e + 8 <= e1; e += 8) {
    const int s0 = csr[e], s1 = csr[e + 1], s2 = csr[e + 2], s3 = csr[e + 3];
    const int s4 = csr[e + 4], s5 = csr[e + 5], s6 = csr[e + 6], s7 = csr[e + 7];
    const u32 v0 = xs[(size_t)s0 * 64 + l];
    const u32 v1 = xs[(size_t)s1 * 64 + l];
    const u32 v2 = xs[(size_t)s2 * 64 + l];
    const u32 v3 = xs[(size_t)s3 * 64 + l];
    const u32 v4 = xs[(size_t)s4 * 64 + l];
    const u32 v5 = xs[(size_t)s5 * 64 + l];
    const u32 v6 = xs[(size_t)s6 * 64 + l];
    const u32 v7 = xs[(size_t)s7 * 64 + l];
    a0 += blo(v0); a1 += bhi(v0);
    a0 += blo(v1); a1 += bhi(v1);
    a0 += blo(v2); a1 += bhi(v2);
    a0 += blo(v3); a1 += bhi(v3);
    a0 += blo(v4); a1 += bhi(v4);
    a0 += blo(v5); a1 += bhi(v5);
    a0 += blo(v6); a1 += bhi(v6);
    a0 += blo(v7); a1 += bhi(v7);
  }
  for (; e < e1; ++e) {
    const u32 v = xs[(size_t)csr[e] * 64 + l];
    a0 += blo(v);
    a1 += bhi(v);
  }
  a0 *= dn;
  a1 *= dn;
  ax16[(size_t)node * 64 + l] = (u32)f2h(a0) | ((u32)f2h(a1) << 16);
}

// ---------- gemmkan v2: grouped-ILP K0, permuted LDS tile ----------
// Phase A stores h at permuted col pcol(c)=(c&3)*32+(c>>2), so K0's lane
// (rc,kb) reads 32 inputs CONTIGUOUSLY at hT[rc][kb*32..+31] (8 x b128).
// K0 groups of 4: one float4 load -> 4 INDEPENDENT featfrag chains -> 4 MFMA
// on 2 alternating accumulators (r19: serial chain kept VALUBusy at 29%).
__global__ __launch_bounds__(256, 3) void gemmkan(
    const u32* __restrict__ ax16, const u32* __restrict__ W16,
    const float* __restrict__ bias, const u16* __restrict__ p0h,
    const u16* __restrict__ p1h, float* __restrict__ out) {
  __shared__ float hT[4][16][132];
  __shared__ float hidT[4][16][17];
  const int wv = threadIdx.x >> 6;
  const int l = threadIdx.x & 63;
  const int m0 = (blockIdx.x * 4 + wv) * 16;
  if (m0 >= NN) return;
  const int rc = l & 15, kb = l >> 4;
  // ---- Phase A: GCN GEMM ----
  {
    uint4 a[4];
#pragma unroll
    for (int s = 0; s < 4; ++s)
      a[s] = *(const uint4*)&ax16[(size_t)(m0 + rc) * 64 + s * 16 + kb * 4];
    f32x4 acc[8];
#pragma unroll
    for (int t = 0; t < 8; ++t) acc[t] = (f32x4){0.f, 0.f, 0.f, 0.f};
#pragma unroll
    for (int t = 0; t < 8; ++t) {
#pragma unroll
      for (int s = 0; s < 4; ++s) {
        uint4 b = *(const uint4*)&W16[(size_t)(t * 16 + rc) * 64 + s * 16 + kb * 4];
        acc[t] = __builtin_amdgcn_mfma_f32_16x16x32_f16(as_half8(a[s]), as_half8(b),
                                                        acc[t], 0, 0, 0);
      }
    }
    // store with permuted col: c = t*16+rc -> (rc&3)*32 + (rc>>2) + t*4
    const int pbase = (rc & 3) * 32 + (rc >> 2);
#pragma unroll
    for (int t = 0; t < 8; ++t) {
      const float bo = bias[t * 16 + rc];
#pragma unroll
      for (int r = 0; r < 4; ++r) {
        hT[wv][kb * 4 + r][pbase + t * 4] = acc[t][r] + bo;
      }
    }
  }
  __builtin_amdgcn_s_waitcnt(0);  // wave-local LDS ordering (r17-proven)
  // ---- K0: 8 groups x (1 b128 LDS load, 4 independent featfrags, 4 MFMA) ----
  const float* hrow = &hT[wv][rc][kb * 32];
  f32x4 accA = (f32x4){0.f, 0.f, 0.f, 0.f};
  f32x4 accB = (f32x4){0.f, 0.f, 0.f, 0.f};
#pragma unroll
  for (int g = 0; g < 8; ++g) {
    float4 hv = *(const float4*)&hrow[g * 4];
    uint4 f0 = featfrag(hv.x);
    uint4 f1 = featfrag(hv.y);
    uint4 f2 = featfrag(hv.z);
    uint4 f3 = featfrag(hv.w);
    uint4 b0 = *(const uint4*)&p0h[rc * 1024 + (g * 4 + 0) * 32 + kb * 8];
    uint4 b1 = *(const uint4*)&p0h[rc * 1024 + (g * 4 + 1) * 32 + kb * 8];
    uint4 b2 = *(const uint4*)&p0h[rc * 1024 + (g * 4 + 2) * 32 + kb * 8];
    uint4 b3 = *(const uint4*)&p0h[rc * 1024 + (g * 4 + 3) * 32 + kb * 8];
    accA = __builtin_amdgcn_mfma_f32_16x16x32_f16(as_half8(f0), as_half8(b0), accA, 0, 0, 0);
    accB = __builtin_amdgcn_mfma_f32_16x16x32_f16(as_half8(f1), as_half8(b1), accB, 0, 0, 0);
    accA = __builtin_amdgcn_mfma_f32_16x16x32_f16(as_half8(f2), as_half8(b2), accA, 0, 0, 0);
    accB = __builtin_amdgcn_mfma_f32_16x16x32_f16(as_half8(f3), as_half8(b3), accB, 0, 0, 0);
  }
  f32x4 acc0 = accA + accB;
  // ---- transpose hid within the wave ----
#pragma unroll
  for (int r = 0; r < 4; ++r) hidT[wv][kb * 4 + r][rc] = acc0[r];
  __builtin_amdgcn_s_waitcnt(0);
  // ---- K1 A-fragments (4 independent chains) ----
  uint4 af0 = featfrag(hidT[wv][rc][0 * 4 + kb]);
  uint4 af1 = featfrag(hidT[wv][rc][1 * 4 + kb]);
  uint4 af2 = featfrag(hidT[wv][rc][2 * 4 + kb]);
  uint4 af3 = featfrag(hidT[wv][rc][3 * 4 + kb]);
  // ---- K1: 8 output tiles x 4 k-steps ----
  f32x4 acc1[8];
#pragma unroll
  for (int t = 0; t < 8; ++t) acc1[t] = (f32x4){0.f, 0.f, 0.f, 0.f};
#pragma unroll
  for (int t = 0; t < 8; ++t) {
    const u16* prow = &p1h[(size_t)(t * 16 + rc) * 128];
    uint4 b0 = *(const uint4*)&prow[0 * 32 + kb * 8];
    uint4 b1 = *(const uint4*)&prow[1 * 32 + kb * 8];
    uint4 b2 = *(const uint4*)&prow[2 * 32 + kb * 8];
    uint4 b3 = *(const uint4*)&prow[3 * 32 + kb * 8];
    acc1[t] = __builtin_amdgcn_mfma_f32_16x16x32_f16(as_half8(af0), as_half8(b0), acc1[t], 0, 0, 0);
    acc1[t] = __builtin_amdgcn_mfma_f32_16x16x32_f16(as_half8(af1), as_half8(b1), acc1[t], 0, 0, 0);
    acc1[t] = __builtin_amdgcn_mfma_f32_16x16x32_f16(as_half8(af2), as_half8(b2), acc1[t], 0, 0, 0);
    acc1[t] = __builtin_amdgcn_mfma_f32_16x16x32_f16(as_half8(af3), as_half8(b3), acc1[t], 0, 0, 0);
  }
#pragma unroll
  for (int t = 0; t < 8; ++t) {
#pragma unroll
    for (int r = 0; r < 4; ++r) {
      out[(size_t)(m0 + kb * 4 + r) * C + t * 16 + rc] = acc1[t][r];
    }
  }
}

extern "C" void kernel_launch(void* const* d_in, const int* in_sizes, int n_in,
                              void* d_out, int out_size, void* d_ws, size_t ws_size,
                              hipStream_t stream) {
  const float* x   = (const float*)d_in[0];
  const int*   ei  = (const int*)d_in[1];
  const float* gw  = (const float*)d_in[2];
  const float* gb  = (const float*)d_in[3];
  const float* bw0 = (const float*)d_in[4];
  const float* sw0 = (const float*)d_in[5];
  const float* sc0 = (const float*)d_in[6];
  const float* bw1 = (const float*)d_in[7];
  const float* sw1 = (const float*)d_in[8];
  const float* sc1 = (const float*)d_in[9];
  float* out = (float*)d_out;

  char* p = (char*)d_ws;
  u32* W16 = (u32*)p;         p += C * C * 2;
  u16* p0h = (u16*)p;         p += H * C * 8 * 2;
  u16* p1h = (u16*)p;         p += C * H * 8 * 2;
  float* dinv = (float*)p;    p += NN * 4;
  int* cnt = (int*)p;         p += NN * 4;
  int* excl = (int*)p;        p += NN * 4;
  int* bsums = (int*)p;       p += 256 * 4;
  int* row_start = (int*)p;   p += (NN + 4) * 4;
  u16* slot = (u16*)p;        p += (size_t)NE * 2;       // 1.6 MB
  u16* csr = (u16*)p;         p += (size_t)NE * 2;       // 1.6 MB
  p = (char*)(((size_t)p + 15) & ~(size_t)15);
  u32* xs = (u32*)p;          p += (size_t)NN * C * 2;   // 12.8 MB
  u32* ax16 = (u32*)p;        p += (size_t)NN * C * 2;   // 12.8 MB

  const int* src = ei;
  const int* dst = ei + NE;

  prep_w<<<196, 256, 0, stream>>>(gw, bw0, sw0, sc0, bw1, sw1, sc1, W16, p0h, p1h, cnt);
  count_kernel<<<(NE + 255) / 256, 256, 0, stream>>>(dst, cnt, slot);
  scan1<<<196, 256, 0, stream>>>(cnt, excl, bsums, NN);
  scan3<<<196, 256, 0, stream>>>(excl, bsums, cnt, row_start, dinv, NN, 196);
  xs_prep<<<(NN * C / 4 + 255) / 256, 256, 0, stream>>>(x, dinv, xs);
  fill_kernel<<<(NE + 255) / 256, 256, 0, stream>>>(src, dst, slot, row_start, csr);
  agg_kernel<<<NN / 4, 256, 0, stream>>>(xs, csr, row_start, dinv, ax16);
  gemmkan<<<(NN + 63) / 64, 256, 0, stream>>>(ax16, W16, gb, p0h, p1h, out);
}